// Round 13
// baseline (510.694 us; speedup 1.0000x reference)
//
#include <hip/hip_runtime.h>
#include <cstdint>
#include <cstddef>

#define THREADS 256

typedef __attribute__((ext_vector_type(8))) short bf16x8;
typedef __attribute__((ext_vector_type(4))) float f32x4;
typedef __attribute__((ext_vector_type(2))) float f32x2;

// ---------------------------------------------------------------------------
// JAX threefry2x32 (Random123, 20 rounds) — used for the dropout masks.
// jax_threefry_partitionable=True semantics (verified R1: absmax 0.0156):
// split keys = tf(key,(0,j)); bits[i] = o0^o1 of tf(key,(0,i)).
// ---------------------------------------------------------------------------
__host__ __device__ __forceinline__ void tf2x32(unsigned k0, unsigned k1,
                                                unsigned x0, unsigned x1,
                                                unsigned* o0, unsigned* o1) {
  unsigned ks2 = k0 ^ k1 ^ 0x1BD11BDAu;
  x0 += k0; x1 += k1;
#define TFR(r) { x0 += x1; x1 = (x1 << (r)) | (x1 >> (32 - (r))); x1 ^= x0; }
  TFR(13) TFR(15) TFR(26) TFR(6)   x0 += k1;  x1 += ks2 + 1u;
  TFR(17) TFR(29) TFR(16) TFR(24)  x0 += ks2; x1 += k0 + 2u;
  TFR(13) TFR(15) TFR(26) TFR(6)   x0 += k0;  x1 += k1 + 3u;
  TFR(17) TFR(29) TFR(16) TFR(24)  x0 += k1;  x1 += ks2 + 4u;
  TFR(13) TFR(15) TFR(26) TFR(6)   x0 += ks2; x1 += k0 + 5u;
#undef TFR
  *o0 = x0; *o1 = x1;
}

// fp32 -> bf16 with round-to-nearest-even (matches XLA convert semantics).
__device__ __forceinline__ unsigned f2bf(float f) {
  unsigned b = __float_as_uint(f);
  return (b + 0x7fffu + ((b >> 16) & 1u)) >> 16;
}

// fp32 -> fp8 e4m3 (OCP) via HW cvt (RNE+sat); returns the byte.
__device__ __forceinline__ unsigned char f2fp8(float f) {
  return (unsigned char)(__builtin_amdgcn_cvt_pk_fp8_f32(f, f, 0, false) & 0xff);
}

// Fused BN-affine + ReLU + dropout on 8 consecutive elements of one row,
// using a PRECOMPUTED per-row bitmask (e = even-col bits, o = odd-col bits,
// bit p ↔ cols col0+2p / col0+2p+1). R7: threefry/BN-coef math inside the
// GEMM cost a VGPR occupancy cliff. R21: masks come from bn_stats.
__device__ __forceinline__ void bn_mask8(float* v, const float* __restrict__ scsh,
                                         int col0, unsigned e, unsigned o) {
  float sc[8], sh[8];
  *(float4*)&sc[0] = *(const float4*)(scsh + col0);
  *(float4*)&sc[4] = *(const float4*)(scsh + col0 + 4);
  *(float4*)&sh[0] = *(const float4*)(scsh + 128 + col0);
  *(float4*)&sh[4] = *(const float4*)(scsh + 128 + col0 + 4);
#pragma unroll
  for (int p = 0; p < 4; ++p) {
    float t0 = fmaxf(v[2 * p] * sc[2 * p] + sh[2 * p], 0.f);
    float t1 = fmaxf(v[2 * p + 1] * sc[2 * p + 1] + sh[2 * p + 1], 0.f);
    v[2 * p] = ((e >> p) & 1u) ? 2.f * t0 : 0.f;
    v[2 * p + 1] = ((o >> p) & 1u) ? 2.f * t1 : 0.f;
  }
}

// ---------------------------------------------------------------------------
// CSR build, R20 (measured 513.7 µs): LDS-staged block binning.
// Ladder: R14 shared counters 437 µs → R15 XCD-local 120 → R16 no deg
// atomics 95 → R18 stride-8 counters 73.6 → R20 LDS histogram + dense
// writeout (~25 µs, out of top-5). DO NOT TOUCH — measured good.
// ---------------------------------------------------------------------------
__global__ __launch_bounds__(THREADS) void compute_deg(const int* __restrict__ dst,
                                                       int* __restrict__ deg, int E) {
  int e = blockIdx.x * THREADS + threadIdx.x;
  if (e < E) atomicAdd(&deg[dst[e]], 1);
}

#define BIN_TILE 4096
#define EPT 16                      // BIN_TILE / THREADS
__global__ __launch_bounds__(THREADS) void bin_edges3(
    const int* __restrict__ src, const int* __restrict__ dst,
    unsigned* __restrict__ bcnt, unsigned* __restrict__ buckets,
    int cap, int nbk, int E, int e8, unsigned nmax) {
  __shared__ unsigned hist[1024];
  __shared__ unsigned lofs[1024];
  __shared__ unsigned gbase[1024];
  __shared__ unsigned part[THREADS];
  __shared__ unsigned img[BIN_TILE];
  __shared__ unsigned opos[BIN_TILE];
  __shared__ int s_total;
  int g = blockIdx.x & 7;
  int chunk = blockIdx.x >> 3;
  int nchunk = gridDim.x >> 3;
  int lo = g * e8;
  int hi = lo + e8; if (hi > E) hi = E;
  unsigned* mycnt = bcnt + (size_t)g * nbk * 8;       // R18 layout: stride 8
  unsigned* mybkt = buckets + (size_t)g * nbk * cap;  // XCD-local storage
  int t = threadIdx.x;
  for (int tile = lo + chunk * BIN_TILE; tile < hi; tile += nchunk * BIN_TILE) {
    // phase A: clear histogram
    for (int i = t; i < 1024; i += THREADS) hist[i] = 0;
    __syncthreads();
    // phase B: count (local slot per edge kept in regs)
    unsigned l[EPT];
#pragma unroll
    for (int j = 0; j < EPT; ++j) {
      int e = tile + j * THREADS + t;               // coalesced
      l[j] = 0xFFFFFFFFu;
      if (e < hi) {
        unsigned d = (unsigned)dst[e];
        if (d < nmax) l[j] = atomicAdd(&hist[d >> 7], 1u);
      }
    }
    __syncthreads();
    // phase C: exclusive scan of hist (each thread owns 4 buckets)
    unsigned c0 = hist[t * 4], c1 = hist[t * 4 + 1];
    unsigned c2 = hist[t * 4 + 2], c3 = hist[t * 4 + 3];
    part[t] = c0 + c1 + c2 + c3;
    __syncthreads();
    for (int off = 1; off < THREADS; off <<= 1) {
      unsigned v = (t >= off) ? part[t - off] : 0u;
      __syncthreads();
      part[t] += v;
      __syncthreads();
    }
    unsigned run = (t > 0) ? part[t - 1] : 0u;
    lofs[t * 4] = run; run += c0;
    lofs[t * 4 + 1] = run; run += c1;
    lofs[t * 4 + 2] = run; run += c2;
    lofs[t * 4 + 3] = run;
    // phase D: one global reservation per non-empty bucket
    for (int b = t; b < nbk; b += THREADS) {
      unsigned c = hist[b];
      if (c) gbase[b] = atomicAdd(&mycnt[(size_t)b * 8], c);
    }
    if (t == 0) s_total = (int)part[THREADS - 1];
    __syncthreads();
    // phase E: place payloads bucket-sorted in LDS (re-read edges, L2-hot)
#pragma unroll
    for (int j = 0; j < EPT; ++j) {
      if (l[j] != 0xFFFFFFFFu) {
        int e = tile + j * THREADS + t;
        unsigned d = (unsigned)dst[e];
        unsigned s = (unsigned)src[e];
        int b = d >> 7;
        unsigned sidx = lofs[b] + l[j];
        img[sidx] = ((d & 127u) << 17) | s;
        unsigned gp = gbase[b] + l[j];
        opos[sidx] = (gp < (unsigned)cap) ? (unsigned)b * cap + gp : 0xFFFFFFFFu;
      }
    }
    __syncthreads();
    // phase F: dense writeout (runs of ~5 consecutive positions per bucket)
    for (int i = t; i < s_total; i += THREADS) {
      unsigned op = opos[i];
      if (op != 0xFFFFFFFFu) mybkt[op] = img[i];
    }
    __syncthreads();
  }
}

// Bucket totals → exclusive scan. One block, 1024 threads; nbk <= 1023.
__global__ __launch_bounds__(1024) void scan_buckets(const unsigned* __restrict__ bcnt,
                                                     int* __restrict__ bbase,
                                                     int cap, int nbk) {
  __shared__ int sdata[1024];
  int t = threadIdx.x;
  int tot = 0;
  if (t < nbk) {
#pragma unroll
    for (int g = 0; g < 8; ++g) {
      int c = (int)bcnt[((size_t)g * nbk + t) * 8];
      tot += (c > cap) ? cap : c;
    }
  }
  sdata[t] = tot;
  __syncthreads();
  for (int off = 1; off < 1024; off <<= 1) {
    int v = (t >= off) ? sdata[t - off] : 0;
    __syncthreads();
    sdata[t] += v;
    __syncthreads();
  }
  if (t < nbk) bbase[t] = sdata[t] - tot;      // exclusive
  if (t == nbk - 1) bbase[nbk] = sdata[t];     // total binned edges
}

#define BCAP_LDS 6144
__global__ __launch_bounds__(THREADS) void scatter_csr2(
    const unsigned* __restrict__ buckets, const unsigned* __restrict__ bcnt,
    const int* __restrict__ bbase, int* __restrict__ deg, int* __restrict__ start,
    int* __restrict__ colbuf, int cap, int nbk, int N) {
  __shared__ unsigned img[BCAP_LDS];
  __shared__ int cnt[128], scanv[128], cnt2[128];
  int b = blockIdx.x;
  int t = threadIdx.x;
  if (t < 128) { cnt[t] = 0; cnt2[t] = 0; }
  __syncthreads();
  // pass A: count per-node occupancy (LDS atomics — cheap)
  for (int g = 0; g < 8; ++g) {
    int mg = (int)bcnt[((size_t)g * nbk + b) * 8]; if (mg > cap) mg = cap;
    const unsigned* bk = buckets + ((size_t)g * nbk + b) * cap;
    for (int i = t; i < mg; i += THREADS)
      atomicAdd(&cnt[(bk[i] >> 17) & 127], 1);
  }
  __syncthreads();
  // inclusive scan of cnt over 128 entries (threads 0..127 active)
  if (t < 128) scanv[t] = cnt[t];
  __syncthreads();
  for (int off = 1; off < 128; off <<= 1) {
    int v = 0;
    if (t < 128 && t >= off) v = scanv[t - off];
    __syncthreads();
    if (t < 128) scanv[t] += v;
    __syncthreads();
  }
  int segbase = bbase[b];
  int seglen = bbase[b + 1] - segbase;
  if (t < 128) {
    int node = (b << 7) + t;
    if (node < N) {
      deg[node] = cnt[t];
      start[node] = segbase + scanv[t] - cnt[t];
    }
  }
  __syncthreads();
  bool fits = (seglen <= BCAP_LDS);
  // pass B: place entries (bucket re-read is L2-warm, ~8 KB/bucket)
  for (int g = 0; g < 8; ++g) {
    int mg = (int)bcnt[((size_t)g * nbk + b) * 8]; if (mg > cap) mg = cap;
    const unsigned* bk = buckets + ((size_t)g * nbk + b) * cap;
    for (int i = t; i < mg; i += THREADS) {
      unsigned v = bk[i];
      int dl = (v >> 17) & 127;
      int pos = scanv[dl] - cnt[dl] + atomicAdd(&cnt2[dl], 1);
      if (fits) {
        if (pos >= 0 && pos < BCAP_LDS) img[pos] = v & 0x1FFFFu;
      } else {
        colbuf[segbase + pos] = (int)(v & 0x1FFFFu);
      }
    }
  }
  __syncthreads();
  if (fits) {
    for (int i = t; i < seglen; i += THREADS)
      colbuf[segbase + i] = (int)img[i];
  }
}

__global__ __launch_bounds__(THREADS) void scan1_local(const int* __restrict__ deg,
                                                       int* __restrict__ start,
                                                       int* __restrict__ blksum, int n) {
  __shared__ int sdata[THREADS];
  int i = blockIdx.x * THREADS + threadIdx.x;
  int d = (i < n) ? deg[i] : 0;
  sdata[threadIdx.x] = d;
  __syncthreads();
  for (int off = 1; off < THREADS; off <<= 1) {
    int v = (threadIdx.x >= off) ? sdata[threadIdx.x - off] : 0;
    __syncthreads();
    sdata[threadIdx.x] += v;
    __syncthreads();
  }
  if (i < n) start[i] = sdata[threadIdx.x] - d;  // local exclusive
  if (threadIdx.x == THREADS - 1) blksum[blockIdx.x] = sdata[THREADS - 1];
}

__global__ __launch_bounds__(512) void scan2_blocks(const int* __restrict__ blksum,
                                                    int* __restrict__ blkbase, int nb) {
  __shared__ int sdata[512];
  int t = threadIdx.x;
  int v = (t < nb) ? blksum[t] : 0;
  sdata[t] = v;
  __syncthreads();
  for (int off = 1; off < 512; off <<= 1) {
    int u = (t >= off) ? sdata[t - off] : 0;
    __syncthreads();
    sdata[t] += u;
    __syncthreads();
  }
  if (t < nb) blkbase[t] = sdata[t] - v;  // exclusive
}

__global__ __launch_bounds__(THREADS) void scan3_add(int* __restrict__ start,
                                                     const int* __restrict__ blkbase,
                                                     int n) {
  int i = blockIdx.x * THREADS + threadIdx.x;
  if (i < n) start[i] += blkbase[blockIdx.x];
}

__global__ __launch_bounds__(THREADS) void fill_csr_xcd(const int* __restrict__ src,
                                                        const int* __restrict__ dst,
                                                        const int* __restrict__ start,
                                                        int* __restrict__ fill,
                                                        int* __restrict__ colbuf,
                                                        int E, int rngw) {
  int g = blockIdx.x & 7;
  int chunk = blockIdx.x >> 3;
  int nchunk = gridDim.x >> 3;
  int lo = g * rngw, hi = lo + rngw;
  int stride = nchunk * THREADS;
  for (int e = chunk * THREADS + threadIdx.x; e < E; e += stride) {
    int d = dst[e];
    if (d >= lo && d < hi) {
      int p = atomicAdd(&fill[d], 1);
      colbuf[start[d] + p] = src[e];
    }
  }
}

// ---------------------------------------------------------------------------
// Pack [Wl | Wr] into MFMA B-fragment order (uint4 per (nt,kc,quad,n)).
// ---------------------------------------------------------------------------
__global__ __launch_bounds__(THREADS) void pack_weights(const float* __restrict__ Wl,
                                                        const float* __restrict__ Wr,
                                                        uint4* __restrict__ Wp) {
  int idx = blockIdx.x * THREADS + threadIdx.x;   // 0..4095
  int n = idx & 15, quad = (idx >> 4) & 3, kc = (idx >> 6) & 3, nt = idx >> 8;
  const float* W = (nt < 8) ? Wl : Wr;
  int col = ((nt & 7) * 16) + n;
  int k0 = kc * 32 + quad * 8;
  unsigned u[4];
#pragma unroll
  for (int p = 0; p < 4; ++p) {
    unsigned lo = f2bf(W[(size_t)(k0 + 2 * p) * 128 + col]);
    unsigned hi = f2bf(W[(size_t)(k0 + 2 * p + 1) * 128 + col]);
    u[p] = lo | (hi << 16);
  }
  Wp[idx] = make_uint4(u[0], u[1], u[2], u[3]);
}

// ---------------------------------------------------------------------------
// Half GEMM via MFMA bf16 (R23 split of the dual kernel).
// R22 post-mortem: dual kernel = 62 µs at Occupancy 24.5%, MfmaUtil 3.8%,
// VALUBusy 11.5% — latency-bound with too few waves (6250) and a heavy
// per-wave VMEM chain. Split: PASS 0 → Cl = fp8(A'@Wl); PASS 1 → Cr =
// A'@Wr + bias. Launched back-to-back on the stream; ORDER MATTERS for
// layer 2 (Cr in-place on buf1): Cl dispatch reads ALL of buf1 before the
// Cr dispatch overwrites it (stream serialization + block-local reg
// staging). Halved register/VMEM budget per wave → higher occupancy.
// A-frag: A[m=lane&15][k=quad*8+j]; C/D: col=lane&15, row=quad*4+reg.
// ---------------------------------------------------------------------------
template <int FUSE, int PASS>
__global__ __launch_bounds__(THREADS) void gemm_half_mfma(
    const float* A, const uint4* __restrict__ Wp, const float* __restrict__ bias,
    const float* __restrict__ scsh, const unsigned long long* __restrict__ mask,
    unsigned char* __restrict__ Cl, float* __restrict__ Cr, int M) {
  int t = threadIdx.x;
  int wv = t >> 6;
  int lane = t & 63;
  int m16 = lane & 15;
  int quad = lane >> 4;
  int arow = blockIdx.x * 64 + wv * 16 + m16;     // A row this lane feeds
  bool avalid = arow < M;

  union U8 { uint4 u; bf16x8 v; };

  unsigned long long m0 = 0, m1 = 0;
  if (FUSE && avalid) {
    m0 = mask[2 * (size_t)arow];
    m1 = mask[2 * (size_t)arow + 1];
  }

  bf16x8 af[4];
  const float* ap = A + (size_t)arow * 128 + quad * 8;
#pragma unroll
  for (int kc = 0; kc < 4; ++kc) {
    float v[8] = {0.f, 0.f, 0.f, 0.f, 0.f, 0.f, 0.f, 0.f};
    if (avalid) {
      *(float4*)&v[0] = *(const float4*)(ap + kc * 32);
      *(float4*)&v[4] = *(const float4*)(ap + kc * 32 + 4);
    }
    if (FUSE) {
      int col0 = kc * 32 + quad * 8;
      int shift = (col0 >> 1);                    // = kc*16 + quad*4
      unsigned e = (unsigned)(m0 >> shift) & 0xFu;
      unsigned o = (unsigned)(m1 >> shift) & 0xFu;
      bn_mask8(v, scsh, col0, e, o);
    }
    U8 u;
    u.u.x = f2bf(v[0]) | (f2bf(v[1]) << 16);
    u.u.y = f2bf(v[2]) | (f2bf(v[3]) << 16);
    u.u.z = f2bf(v[4]) | (f2bf(v[5]) << 16);
    u.u.w = f2bf(v[6]) | (f2bf(v[7]) << 16);
    af[kc] = u.v;
  }

  int orow0 = blockIdx.x * 64 + wv * 16 + quad * 4;
  const uint4* wp = Wp + m16;   // + ((nt*4+kc)*4+quad)*16

  f32x4 acc[8];
#pragma unroll
  for (int i = 0; i < 8; ++i) acc[i] = (f32x4){0.f, 0.f, 0.f, 0.f};
#pragma unroll
  for (int nt = 0; nt < 8; ++nt) {
#pragma unroll
    for (int kc = 0; kc < 4; ++kc) {
      U8 b;
      b.u = wp[(((nt + (PASS ? 8 : 0)) * 4 + kc) * 4 + quad) * 16];
      acc[nt] = __builtin_amdgcn_mfma_f32_16x16x32_bf16(af[kc], b.v, acc[nt], 0, 0, 0);
    }
  }
  if (PASS == 0) {
#pragma unroll
    for (int nt = 0; nt < 8; ++nt) {
      int col = nt * 16 + m16;
#pragma unroll
      for (int r = 0; r < 4; ++r) {
        int row = orow0 + r;
        if (row < M) Cl[(size_t)row * 128 + col] = f2fp8(acc[nt][r]);
      }
    }
  } else {
#pragma unroll
    for (int nt = 0; nt < 8; ++nt) {
      int col = nt * 16 + m16;
      float bb = bias[col];
#pragma unroll
      for (int r = 0; r < 4; ++r) {
        int row = orow0 + r;
        if (row < M) Cr[(size_t)row * 128 + col] = acc[nt][r] + bb;
      }
    }
  }
}

// ---------------------------------------------------------------------------
// Fused layer-3 projections: Cl = bf16(A'@Wl), Cr = A'@Wr + br, where
// A' = mask2*2*relu(scsh2-affine(A)) applied on load. Reads A ONCE.
// Layer-3 Cl stays BF16: its aggregate feeds `out` directly (no BN to absorb
// fp8 noise) and agg16 is cheap anyway.
// ---------------------------------------------------------------------------
__global__ __launch_bounds__(THREADS) void gemm16_dual(const float* __restrict__ A,
                                                       const float* __restrict__ Wl,
                                                       const float* __restrict__ Wr,
                                                       const float* __restrict__ br,
                                                       const float* __restrict__ scsh,
                                                       const unsigned long long* __restrict__ mask,
                                                       unsigned short* __restrict__ Cl,
                                                       float* __restrict__ Cr, int M) {
  __shared__ __align__(16) float Wls[128][16];  // [k][col]
  __shared__ __align__(16) float Wrs[128][16];
  __shared__ __align__(16) float As[16][130];   // [row][k], +2 pad
  int t = threadIdx.x;
#pragma unroll
  for (int i = 0; i < 2; ++i) {
    int lin = (t + i * THREADS) << 2;           // float4 id → float offset
    *(float4*)&Wls[0][lin & 2047] = *(const float4*)(Wl + lin);
    *(float4*)&Wrs[0][lin & 2047] = *(const float4*)(Wr + lin);
  }
  int row0 = blockIdx.x * 16;
  int r = t >> 4;     // 0..15 local row
  int c = t & 15;     // col / chunk id
  {
    int grow = row0 + r;
    float v[8] = {0.f, 0.f, 0.f, 0.f, 0.f, 0.f, 0.f, 0.f};
    if (grow < M) {
      const float* ap = A + (size_t)grow * 128 + c * 8;
      *(float4*)&v[0] = *(const float4*)(ap);
      *(float4*)&v[4] = *(const float4*)(ap + 4);
      unsigned long long m0 = mask[2 * (size_t)grow];
      unsigned long long m1 = mask[2 * (size_t)grow + 1];
      int shift = c * 4;                         // (c*8)/2
      unsigned e = (unsigned)(m0 >> shift) & 0xFu;
      unsigned o = (unsigned)(m1 >> shift) & 0xFu;
      bn_mask8(v, scsh, c * 8, e, o);
    }
    *(float4*)&As[r][c * 8] = *(float4*)&v[0];
    *(float4*)&As[r][c * 8 + 4] = *(float4*)&v[4];
  }
  __syncthreads();
  float accl = 0.f, accr = 0.f;
#pragma unroll 4
  for (int k = 0; k < 128; ++k) {
    float a = As[r][k];                          // broadcast across 16 lanes
    accl += a * Wls[k][c];
    accr += a * Wrs[k][c];
  }
  int grow = row0 + r;
  if (grow < M) {
    Cl[(size_t)grow * 16 + c] = (unsigned short)f2bf(accl);
    Cr[(size_t)grow * 16 + c] = accr + br[c];
  }
}

// ---------------------------------------------------------------------------
// Z[n] (fp32) += agg(Yfp8)[n] / max(deg,1): one wave per node; the wave's
// two 32-lane halves process two edges per instruction; lane covers 4 fp8
// cols (uint load = whole 128 B row per half). fp8 rows = 2 lines/edge
// (R10 win). HW pk decode fp8→f32. Cross-half combine via __shfl; lanes
// 0..31 do the float4 Z update. R21: threefry moved out; 16-edge unroll.
// ---------------------------------------------------------------------------
__global__ __launch_bounds__(THREADS) void aggregate128_fp8(
    const unsigned char* __restrict__ Y, float* __restrict__ Z,
    const int* __restrict__ colbuf, const int* __restrict__ start,
    const int* __restrict__ deg, int nnodes) {
  int w = (blockIdx.x * THREADS + threadIdx.x) >> 6;  // node = global wave id
  int lane = threadIdx.x & 63;
  if (w >= nnodes) return;
  int half = lane >> 5;         // 0: even edge of pair, 1: odd edge
  int l32 = lane & 31;
  const int* cb = colbuf + start[w];
  int dg = deg[w];
  const unsigned char* yp = Y + (l32 << 2);      // 4 fp8 cols per lane
  float a0f = 0.f, a1f = 0.f, a2f = 0.f, a3f = 0.f;
  int i = 0;
#define ACC(u) { \
    f32x2 lo = __builtin_amdgcn_cvt_pk_f32_fp8((int)(u), false); \
    f32x2 hi = __builtin_amdgcn_cvt_pk_f32_fp8((int)(u), true);  \
    a0f += lo.x; a1f += lo.y; a2f += hi.x; a3f += hi.y; }
  for (; i + 16 <= dg; i += 16) {                // 16 edges = 8 loads in flight
    int e0 = cb[i + half], e1 = cb[i + 2 + half];
    int e2 = cb[i + 4 + half], e3 = cb[i + 6 + half];
    int e4 = cb[i + 8 + half], e5 = cb[i + 10 + half];
    int e6 = cb[i + 12 + half], e7 = cb[i + 14 + half];
    unsigned u0 = *(const unsigned*)(yp + (size_t)e0 * 128);
    unsigned u1 = *(const unsigned*)(yp + (size_t)e1 * 128);
    unsigned u2 = *(const unsigned*)(yp + (size_t)e2 * 128);
    unsigned u3 = *(const unsigned*)(yp + (size_t)e3 * 128);
    unsigned u4 = *(const unsigned*)(yp + (size_t)e4 * 128);
    unsigned u5 = *(const unsigned*)(yp + (size_t)e5 * 128);
    unsigned u6 = *(const unsigned*)(yp + (size_t)e6 * 128);
    unsigned u7 = *(const unsigned*)(yp + (size_t)e7 * 128);
    ACC(u0) ACC(u1) ACC(u2) ACC(u3) ACC(u4) ACC(u5) ACC(u6) ACC(u7)
  }
  for (; i + 8 <= dg; i += 8) {                  // 8 edges = 4 uint loads/lane
    int e0 = cb[i + half], e1 = cb[i + 2 + half];
    int e2 = cb[i + 4 + half], e3 = cb[i + 6 + half];
    unsigned u0 = *(const unsigned*)(yp + (size_t)e0 * 128);
    unsigned u1 = *(const unsigned*)(yp + (size_t)e1 * 128);
    unsigned u2 = *(const unsigned*)(yp + (size_t)e2 * 128);
    unsigned u3 = *(const unsigned*)(yp + (size_t)e3 * 128);
    ACC(u0) ACC(u1) ACC(u2) ACC(u3)
  }
  for (; i + 2 <= dg; i += 2) {
    int e0 = cb[i + half];
    unsigned u0 = *(const unsigned*)(yp + (size_t)e0 * 128);
    ACC(u0)
  }
  if (i < dg) {                                  // odd tail: half 0 only
    int e0 = cb[i];
    unsigned u0 = *(const unsigned*)(yp + (size_t)e0 * 128);
    if (half == 0) { ACC(u0) }
  }
#undef ACC
  // combine halves: lanes 0..31 += lanes 32..63 (same cols)
  a0f += __shfl(a0f, lane + 32);
  a1f += __shfl(a1f, lane + 32);
  a2f += __shfl(a2f, lane + 32);
  a3f += __shfl(a3f, lane + 32);

  if (half == 0) {
    float sc = 1.0f / fmaxf((float)dg, 1.0f);
    float* zp = Z + (size_t)w * 128 + (l32 << 2);
    float4 z = *(const float4*)zp;
    z.x += a0f * sc;
    z.y += a1f * sc;
    z.z += a2f * sc;
    z.w += a3f * sc;
    *(float4*)zp = z;
  }
}

// Out[n] += agg(Y16bf16)[n] / max(deg,1): 8 threads/node, ×8 edge unroll.
__global__ __launch_bounds__(THREADS) void aggregate16_bf16(
    const unsigned short* __restrict__ Y, float* __restrict__ Out,
    const int* __restrict__ colbuf, const int* __restrict__ start,
    const int* __restrict__ deg, int nnodes) {
  int gid = blockIdx.x * THREADS + threadIdx.x;
  int n = gid >> 3;
  int cp = gid & 7;             // col pair: cols 2cp, 2cp+1
  if (n >= nnodes) return;
  const int* cb = colbuf + start[n];
  int dg = deg[n];
  const unsigned short* yp = Y + (cp << 1);
  float ax = 0.f, ay = 0.f;
  int i = 0;
  for (; i + 8 <= dg; i += 8) {
    int e[8];
#pragma unroll
    for (int j = 0; j < 8; ++j) e[j] = cb[i + j];
    unsigned u[8];
#pragma unroll
    for (int j = 0; j < 8; ++j) u[j] = *(const unsigned*)(yp + (size_t)e[j] * 16);
#pragma unroll
    for (int j = 0; j < 8; ++j) {
      ax += __uint_as_float(u[j] << 16);
      ay += __uint_as_float(u[j] & 0xffff0000u);
    }
  }
  for (; i < dg; ++i) {
    unsigned u = *(const unsigned*)(yp + (size_t)cb[i] * 16);
    ax += __uint_as_float(u << 16);
    ay += __uint_as_float(u & 0xffff0000u);
  }
  float sc = 1.0f / fmaxf((float)dg, 1.0f);
  size_t off = (size_t)n * 16 + (cp << 1);
  float2 o = *(const float2*)(Out + off);
  o.x += ax * sc;
  o.y += ay * sc;
  *(float2*)(Out + off) = o;
}

// ---------------------------------------------------------------------------
// BN stats + dropout mask gen (R21 move; R22 ILP fix — measured good).
// 4 rows per iteration with 4 INDEPENDENT threefry chains — ILP covers the
// VALU dep latency. Wave scheme (bit-identical masks): wave parity p,
// lane l → element r*128+2l+p → ballot → mask[2r+p].
// ---------------------------------------------------------------------------
__global__ __launch_bounds__(THREADS) void bn_stats(const float* __restrict__ H,
                                                    float* __restrict__ sums,
                                                    unsigned long long* __restrict__ mask,
                                                    unsigned mk0, unsigned mk1,
                                                    int n) {
  int col = threadIdx.x & 127;
  int half = threadIdx.x >> 7;  // 0/1 (wave-uniform)
  int lane = threadIdx.x & 63;
  unsigned parity = (threadIdx.x >> 6) & 1u;  // wave-uniform
  unsigned base = ((unsigned)lane << 1) + parity;
  float s = 0.f, sq = 0.f;
  int stride = gridDim.x * 2;
  int r = blockIdx.x * 2 + half;
  // 4-row main loop: independent tf chains give the VALU ILP
  for (; r + 3 * stride < n; r += 4 * stride) {
    int r0 = r, r1 = r + stride, r2 = r + 2 * stride, r3 = r + 3 * stride;
    float v0 = H[(size_t)r0 * 128 + col];
    float v1 = H[(size_t)r1 * 128 + col];
    float v2 = H[(size_t)r2 * 128 + col];
    float v3 = H[(size_t)r3 * 128 + col];
    s += v0 + v1 + v2 + v3;
    sq += v0 * v0 + v1 * v1 + v2 * v2 + v3 * v3;
    unsigned a0, a1, b0, b1, c0, c1, d0, d1;
    tf2x32(mk0, mk1, 0u, (unsigned)r0 * 128u + base, &a0, &a1);
    tf2x32(mk0, mk1, 0u, (unsigned)r1 * 128u + base, &b0, &b1);
    tf2x32(mk0, mk1, 0u, (unsigned)r2 * 128u + base, &c0, &c1);
    tf2x32(mk0, mk1, 0u, (unsigned)r3 * 128u + base, &d0, &d1);
    unsigned long long m0b = __ballot(((a0 ^ a1) >> 31) == 0u);
    unsigned long long m1b = __ballot(((b0 ^ b1) >> 31) == 0u);
    unsigned long long m2b = __ballot(((c0 ^ c1) >> 31) == 0u);
    unsigned long long m3b = __ballot(((d0 ^ d1) >> 31) == 0u);
    if (lane == 0) {
      mask[2 * (size_t)r0 + parity] = m0b;
      mask[2 * (size_t)r1 + parity] = m1b;
      mask[2 * (size_t)r2 + parity] = m2b;
      mask[2 * (size_t)r3 + parity] = m3b;
    }
  }
  for (; r < n; r += stride) {
    float v = H[(size_t)r * 128 + col];
    s += v;
    sq += v * v;
    unsigned o0, o1;
    tf2x32(mk0, mk1, 0u, (unsigned)r * 128u + base, &o0, &o1);
    unsigned long long bm = __ballot(((o0 ^ o1) >> 31) == 0u);
    if (lane == 0) mask[2 * (size_t)r + parity] = bm;
  }
  __shared__ float ls[THREADS], lq[THREADS];
  ls[threadIdx.x] = s;
  lq[threadIdx.x] = sq;
  __syncthreads();
  if (half == 0) {
    s += ls[col + 128];
    sq += lq[col + 128];
    atomicAdd(&sums[col], s);
    atomicAdd(&sums[128 + col], sq);
  }
}

__global__ void bn_finalize(const float* __restrict__ sums,
                            const float* __restrict__ g,
                            const float* __restrict__ be,
                            float* __restrict__ scsh, float n) {
  int c = threadIdx.x;  // 128 threads
  float mu = sums[c] / n;
  float var = sums[128 + c] / n - mu * mu;
  float inv = rsqrtf(var + 1e-5f);
  float sc = g[c] * inv;
  scsh[c] = sc;
  scsh[128 + c] = be[c] - mu * sc;
}

// ---------------------------------------------------------------------------
// Launch. R23: dual GEMM split into two half-GEMM dispatches per layer
// (Cl first, then Cr — order is load-before-overwrite for layer-2's
// in-place Cr). Everything else identical to the R22-measured build
// (493.7 µs).
// ---------------------------------------------------------------------------
extern "C" void kernel_launch(void* const* d_in, const int* in_sizes, int n_in,
                              void* d_out, int out_size, void* d_ws, size_t ws_size,
                              hipStream_t stream) {
  const float* x   = (const float*)d_in[0];
  const int* eidx  = (const int*)d_in[1];
  const float* W1l = (const float*)d_in[2];
  const float* W1r = (const float*)d_in[3];
  const float* b1  = (const float*)d_in[4];
  const float* g1  = (const float*)d_in[5];
  const float* be1 = (const float*)d_in[6];
  const float* W2l = (const float*)d_in[7];
  const float* W2r = (const float*)d_in[8];
  const float* b2  = (const float*)d_in[9];
  const float* g2  = (const float*)d_in[10];
  const float* be2 = (const float*)d_in[11];
  const float* W3l = (const float*)d_in[12];
  const float* W3r = (const float*)d_in[13];
  const float* b3  = (const float*)d_in[14];
  float* out = (float*)d_out;

  const int N = in_sizes[0] / 128;
  const int E = in_sizes[1] / 2;
  const int* esrc = eidx;
  const int* edst = eidx + E;

  size_t N128 = (size_t)N * 128;
  size_t Nw = ((size_t)N + 63) & ~(size_t)63;   // padded node count (words)
  size_t Ew = ((size_t)E + 63) & ~(size_t)63;   // padded edge count (words)

  // Cleared region first (one memset): sums1(256) sums2(256) ideg(N) ifill(N)
  float* sums1 = (float*)d_ws;
  float* sums2 = sums1 + 256;
  int* ideg    = (int*)(sums2 + 256);
  int* ifill   = ideg + N;                    // strided bump counters
  // Uncleared (all region sizes padded to multiples of 64 words → every base
  // below is ≥256 B-aligned):
  int* istart  = ifill + N;
  int* iblksum = istart + (int)Nw;            // 512
  int* iblkbase = iblksum + 512;              // 512
  int* bbase   = iblkbase + 512;              // 1088 (bucket-base scan)
  float* scsh1 = (float*)(bbase + 1088);      // 256
  float* scsh2 = scsh1 + 256;                 // 256
  uint4* wp1 = (uint4*)(scsh2 + 256);         // 4096 uint4 each = 64 KB
  uint4* wp2 = wp1 + 4096;
  unsigned long long* mask1 = (unsigned long long*)(wp2 + 4096);  // N×2 u64
  unsigned long long* mask2 = mask1 + 2 * Nw;
  int* icol  = (int*)(mask2 + 2 * Nw);        // E ints
  // buf0: fp8 N×128 B (layers 1-2) / bf16 N×16 (layer 3). 12.8 MB, padded.
  unsigned char* buf0b = (unsigned char*)(icol + Ew);
  unsigned short* buf0h = (unsigned short*)buf0b;
  float* buf1 = (float*)(buf0b + ((N128 + 255) & ~(size_t)255)); // fp32 h-state N×128

  // Bucket storage: overlays buf0/buf1 (dead during CSR build).
  unsigned* buckets = (unsigned*)buf0b;
  int nbk = (N + 127) >> 7;                   // 128-node buckets
  int bcap = 1024;                            // per-(group,bucket) capacity
  size_t bucket_bytes = (size_t)8 * nbk * bcap * 4;
  size_t bufregion_bytes = ((N128 + 255) & ~(size_t)255) + 4 * N128;
  bool newcsr = (N <= 131072) && (nbk <= 1023) &&
                ((size_t)64 * nbk <= (size_t)N) &&   // counters fit cleared region
                (bucket_bytes <= bufregion_bytes);

  // dropout keys: k1,k2 = split(key(42)) under partitionable threefry
  unsigned k1a, k1b, k2a, k2b;
  tf2x32(0u, 42u, 0u, 0u, &k1a, &k1b);
  tf2x32(0u, 42u, 0u, 1u, &k2a, &k2b);

  hipMemsetAsync(sums1, 0, (512 + 2 * (size_t)N) * 4, stream);

  pack_weights<<<16, THREADS, 0, stream>>>(W1l, W1r, wp1);
  pack_weights<<<16, THREADS, 0, stream>>>(W2l, W2r, wp2);

  int gN = (N + THREADS - 1) / THREADS;      // == #scan blocks, must be <=512
  if (newcsr) {
    int e8 = (((E + 7) / 8) + 3) & ~3;       // 4-aligned per-group edge range
    bin_edges3<<<512, THREADS, 0, stream>>>(esrc, edst, (unsigned*)ifill,
                                            buckets, bcap, nbk, E, e8,
                                            (unsigned)N);
    scan_buckets<<<1, 1024, 0, stream>>>((const unsigned*)ifill, bbase,
                                         bcap, nbk);
    scatter_csr2<<<nbk, THREADS, 0, stream>>>(buckets, (const unsigned*)ifill,
                                              bbase, ideg, istart, icol,
                                              bcap, nbk, N);
  } else {
    int gE = (E + THREADS - 1) / THREADS;
    compute_deg<<<gE, THREADS, 0, stream>>>(edst, ideg, E);
    scan1_local<<<gN, THREADS, 0, stream>>>(ideg, istart, iblksum, N);
    scan2_blocks<<<1, 512, 0, stream>>>(iblksum, iblkbase, gN);
    scan3_add<<<gN, THREADS, 0, stream>>>(istart, iblkbase, N);
    int rngw = (N + 7) / 8;
    fill_csr_xcd<<<2048, THREADS, 0, stream>>>(esrc, edst, istart, ifill, icol, E, rngw);
  }

  int gM64 = (N + 63) / 64;
  int gW = (N + 3) / 4;                 // aggregate128: 4 waves/block
  int gA16 = (N * 8 + THREADS - 1) / THREADS;
  float nf = (float)N;

  // ---- Layer 1 (x is read-only input; Cl → buf0, Cr → buf1) ----
  gemm_half_mfma<0, 0><<<gM64, THREADS, 0, stream>>>(x, wp1, b1, nullptr, nullptr,
                                                     buf0b, nullptr, N);
  gemm_half_mfma<0, 1><<<gM64, THREADS, 0, stream>>>(x, wp1, b1, nullptr, nullptr,
                                                     nullptr, buf1, N);
  aggregate128_fp8<<<gW, THREADS, 0, stream>>>(buf0b, buf1, icol, istart, ideg, N);
  bn_stats<<<1024, THREADS, 0, stream>>>(buf1, sums1, mask1, k1a, k1b, N);
  bn_finalize<<<1, 128, 0, stream>>>(sums1, g1, be1, scsh1, nf);

  // ---- Layer 2 (BN1+ReLU+drop1 via scsh1+mask1; Cr in-place on buf1 —
  //      Cl dispatch fully reads buf1 BEFORE the Cr dispatch overwrites) ----
  gemm_half_mfma<1, 0><<<gM64, THREADS, 0, stream>>>(buf1, wp2, b2, scsh1, mask1,
                                                     buf0b, nullptr, N);
  gemm_half_mfma<1, 1><<<gM64, THREADS, 0, stream>>>(buf1, wp2, b2, scsh1, mask1,
                                                     nullptr, buf1, N);
  aggregate128_fp8<<<gW, THREADS, 0, stream>>>(buf0b, buf1, icol, istart, ideg, N);
  bn_stats<<<1024, THREADS, 0, stream>>>(buf1, sums2, mask2, k2a, k2b, N);
  bn_finalize<<<1, 128, 0, stream>>>(sums2, g2, be2, scsh2, nf);

  // ---- Layer 3 (BN2+ReLU+drop2 via scsh2+mask2 in dual 16-wide GEMM) ----
  gemm16_dual<<<(N + 15) / 16, THREADS, 0, stream>>>(buf1, W3l, W3r, b3, scsh2,
                                                     mask2, buf0h, out, N);
  aggregate16_bf16<<<gA16, THREADS, 0, stream>>>(buf0h, out, icol, istart, ideg, N);
}

// Round 14
// 475.622 us; speedup vs baseline: 1.0737x; 1.0737x over previous
//
#include <hip/hip_runtime.h>
#include <cstdint>
#include <cstddef>

#define THREADS 256

typedef __attribute__((ext_vector_type(8))) short bf16x8;
typedef __attribute__((ext_vector_type(4))) float f32x4;
typedef __attribute__((ext_vector_type(2))) float f32x2;

// ---------------------------------------------------------------------------
// JAX threefry2x32 (Random123, 20 rounds) — used for the dropout masks.
// jax_threefry_partitionable=True semantics (verified R1: absmax 0.0156):
// split keys = tf(key,(0,j)); bits[i] = o0^o1 of tf(key,(0,i)).
// ---------------------------------------------------------------------------
__host__ __device__ __forceinline__ void tf2x32(unsigned k0, unsigned k1,
                                                unsigned x0, unsigned x1,
                                                unsigned* o0, unsigned* o1) {
  unsigned ks2 = k0 ^ k1 ^ 0x1BD11BDAu;
  x0 += k0; x1 += k1;
#define TFR(r) { x0 += x1; x1 = (x1 << (r)) | (x1 >> (32 - (r))); x1 ^= x0; }
  TFR(13) TFR(15) TFR(26) TFR(6)   x0 += k1;  x1 += ks2 + 1u;
  TFR(17) TFR(29) TFR(16) TFR(24)  x0 += ks2; x1 += k0 + 2u;
  TFR(13) TFR(15) TFR(26) TFR(6)   x0 += k0;  x1 += k1 + 3u;
  TFR(17) TFR(29) TFR(16) TFR(24)  x0 += k1;  x1 += ks2 + 4u;
  TFR(13) TFR(15) TFR(26) TFR(6)   x0 += ks2; x1 += k0 + 5u;
#undef TFR
  *o0 = x0; *o1 = x1;
}

// fp32 -> bf16 with round-to-nearest-even (matches XLA convert semantics).
__device__ __forceinline__ unsigned f2bf(float f) {
  unsigned b = __float_as_uint(f);
  return (b + 0x7fffu + ((b >> 16) & 1u)) >> 16;
}

// fp32 -> fp8 e4m3 (OCP) via HW cvt (RNE+sat); returns the byte.
__device__ __forceinline__ unsigned char f2fp8(float f) {
  return (unsigned char)(__builtin_amdgcn_cvt_pk_fp8_f32(f, f, 0, false) & 0xff);
}

// Fused BN-affine + ReLU + dropout on 8 consecutive elements of one row,
// using a PRECOMPUTED per-row bitmask (e = even-col bits, o = odd-col bits,
// bit p ↔ cols col0+2p / col0+2p+1). R7: threefry/BN-coef math inside the
// GEMM cost a VGPR occupancy cliff. R21: masks come from bn_stats.
__device__ __forceinline__ void bn_mask8(float* v, const float* __restrict__ scsh,
                                         int col0, unsigned e, unsigned o) {
  float sc[8], sh[8];
  *(float4*)&sc[0] = *(const float4*)(scsh + col0);
  *(float4*)&sc[4] = *(const float4*)(scsh + col0 + 4);
  *(float4*)&sh[0] = *(const float4*)(scsh + 128 + col0);
  *(float4*)&sh[4] = *(const float4*)(scsh + 128 + col0 + 4);
#pragma unroll
  for (int p = 0; p < 4; ++p) {
    float t0 = fmaxf(v[2 * p] * sc[2 * p] + sh[2 * p], 0.f);
    float t1 = fmaxf(v[2 * p + 1] * sc[2 * p + 1] + sh[2 * p + 1], 0.f);
    v[2 * p] = ((e >> p) & 1u) ? 2.f * t0 : 0.f;
    v[2 * p + 1] = ((o >> p) & 1u) ? 2.f * t1 : 0.f;
  }
}

// ---------------------------------------------------------------------------
// CSR build, R20 (measured 513.7 µs): LDS-staged block binning.
// Ladder: R14 shared counters 437 µs → R15 XCD-local 120 → R16 no deg
// atomics 95 → R18 stride-8 counters 73.6 → R20 LDS histogram + dense
// writeout (~25 µs, out of top-5). DO NOT TOUCH — measured good.
// ---------------------------------------------------------------------------
__global__ __launch_bounds__(THREADS) void compute_deg(const int* __restrict__ dst,
                                                       int* __restrict__ deg, int E) {
  int e = blockIdx.x * THREADS + threadIdx.x;
  if (e < E) atomicAdd(&deg[dst[e]], 1);
}

#define BIN_TILE 4096
#define EPT 16                      // BIN_TILE / THREADS
__global__ __launch_bounds__(THREADS) void bin_edges3(
    const int* __restrict__ src, const int* __restrict__ dst,
    unsigned* __restrict__ bcnt, unsigned* __restrict__ buckets,
    int cap, int nbk, int E, int e8, unsigned nmax) {
  __shared__ unsigned hist[1024];
  __shared__ unsigned lofs[1024];
  __shared__ unsigned gbase[1024];
  __shared__ unsigned part[THREADS];
  __shared__ unsigned img[BIN_TILE];
  __shared__ unsigned opos[BIN_TILE];
  __shared__ int s_total;
  int g = blockIdx.x & 7;
  int chunk = blockIdx.x >> 3;
  int nchunk = gridDim.x >> 3;
  int lo = g * e8;
  int hi = lo + e8; if (hi > E) hi = E;
  unsigned* mycnt = bcnt + (size_t)g * nbk * 8;       // R18 layout: stride 8
  unsigned* mybkt = buckets + (size_t)g * nbk * cap;  // XCD-local storage
  int t = threadIdx.x;
  for (int tile = lo + chunk * BIN_TILE; tile < hi; tile += nchunk * BIN_TILE) {
    // phase A: clear histogram
    for (int i = t; i < 1024; i += THREADS) hist[i] = 0;
    __syncthreads();
    // phase B: count (local slot per edge kept in regs)
    unsigned l[EPT];
#pragma unroll
    for (int j = 0; j < EPT; ++j) {
      int e = tile + j * THREADS + t;               // coalesced
      l[j] = 0xFFFFFFFFu;
      if (e < hi) {
        unsigned d = (unsigned)dst[e];
        if (d < nmax) l[j] = atomicAdd(&hist[d >> 7], 1u);
      }
    }
    __syncthreads();
    // phase C: exclusive scan of hist (each thread owns 4 buckets)
    unsigned c0 = hist[t * 4], c1 = hist[t * 4 + 1];
    unsigned c2 = hist[t * 4 + 2], c3 = hist[t * 4 + 3];
    part[t] = c0 + c1 + c2 + c3;
    __syncthreads();
    for (int off = 1; off < THREADS; off <<= 1) {
      unsigned v = (t >= off) ? part[t - off] : 0u;
      __syncthreads();
      part[t] += v;
      __syncthreads();
    }
    unsigned run = (t > 0) ? part[t - 1] : 0u;
    lofs[t * 4] = run; run += c0;
    lofs[t * 4 + 1] = run; run += c1;
    lofs[t * 4 + 2] = run; run += c2;
    lofs[t * 4 + 3] = run;
    // phase D: one global reservation per non-empty bucket
    for (int b = t; b < nbk; b += THREADS) {
      unsigned c = hist[b];
      if (c) gbase[b] = atomicAdd(&mycnt[(size_t)b * 8], c);
    }
    if (t == 0) s_total = (int)part[THREADS - 1];
    __syncthreads();
    // phase E: place payloads bucket-sorted in LDS (re-read edges, L2-hot)
#pragma unroll
    for (int j = 0; j < EPT; ++j) {
      if (l[j] != 0xFFFFFFFFu) {
        int e = tile + j * THREADS + t;
        unsigned d = (unsigned)dst[e];
        unsigned s = (unsigned)src[e];
        int b = d >> 7;
        unsigned sidx = lofs[b] + l[j];
        img[sidx] = ((d & 127u) << 17) | s;
        unsigned gp = gbase[b] + l[j];
        opos[sidx] = (gp < (unsigned)cap) ? (unsigned)b * cap + gp : 0xFFFFFFFFu;
      }
    }
    __syncthreads();
    // phase F: dense writeout (runs of ~5 consecutive positions per bucket)
    for (int i = t; i < s_total; i += THREADS) {
      unsigned op = opos[i];
      if (op != 0xFFFFFFFFu) mybkt[op] = img[i];
    }
    __syncthreads();
  }
}

// Bucket totals → exclusive scan. One block, 1024 threads; nbk <= 1023.
__global__ __launch_bounds__(1024) void scan_buckets(const unsigned* __restrict__ bcnt,
                                                     int* __restrict__ bbase,
                                                     int cap, int nbk) {
  __shared__ int sdata[1024];
  int t = threadIdx.x;
  int tot = 0;
  if (t < nbk) {
#pragma unroll
    for (int g = 0; g < 8; ++g) {
      int c = (int)bcnt[((size_t)g * nbk + t) * 8];
      tot += (c > cap) ? cap : c;
    }
  }
  sdata[t] = tot;
  __syncthreads();
  for (int off = 1; off < 1024; off <<= 1) {
    int v = (t >= off) ? sdata[t - off] : 0;
    __syncthreads();
    sdata[t] += v;
    __syncthreads();
  }
  if (t < nbk) bbase[t] = sdata[t] - tot;      // exclusive
  if (t == nbk - 1) bbase[nbk] = sdata[t];     // total binned edges
}

#define BCAP_LDS 6144
__global__ __launch_bounds__(THREADS) void scatter_csr2(
    const unsigned* __restrict__ buckets, const unsigned* __restrict__ bcnt,
    const int* __restrict__ bbase, int* __restrict__ deg, int* __restrict__ start,
    int* __restrict__ colbuf, int cap, int nbk, int N) {
  __shared__ unsigned img[BCAP_LDS];
  __shared__ int cnt[128], scanv[128], cnt2[128];
  int b = blockIdx.x;
  int t = threadIdx.x;
  if (t < 128) { cnt[t] = 0; cnt2[t] = 0; }
  __syncthreads();
  // pass A: count per-node occupancy (LDS atomics — cheap)
  for (int g = 0; g < 8; ++g) {
    int mg = (int)bcnt[((size_t)g * nbk + b) * 8]; if (mg > cap) mg = cap;
    const unsigned* bk = buckets + ((size_t)g * nbk + b) * cap;
    for (int i = t; i < mg; i += THREADS)
      atomicAdd(&cnt[(bk[i] >> 17) & 127], 1);
  }
  __syncthreads();
  // inclusive scan of cnt over 128 entries (threads 0..127 active)
  if (t < 128) scanv[t] = cnt[t];
  __syncthreads();
  for (int off = 1; off < 128; off <<= 1) {
    int v = 0;
    if (t < 128 && t >= off) v = scanv[t - off];
    __syncthreads();
    if (t < 128) scanv[t] += v;
    __syncthreads();
  }
  int segbase = bbase[b];
  int seglen = bbase[b + 1] - segbase;
  if (t < 128) {
    int node = (b << 7) + t;
    if (node < N) {
      deg[node] = cnt[t];
      start[node] = segbase + scanv[t] - cnt[t];
    }
  }
  __syncthreads();
  bool fits = (seglen <= BCAP_LDS);
  // pass B: place entries (bucket re-read is L2-warm, ~8 KB/bucket)
  for (int g = 0; g < 8; ++g) {
    int mg = (int)bcnt[((size_t)g * nbk + b) * 8]; if (mg > cap) mg = cap;
    const unsigned* bk = buckets + ((size_t)g * nbk + b) * cap;
    for (int i = t; i < mg; i += THREADS) {
      unsigned v = bk[i];
      int dl = (v >> 17) & 127;
      int pos = scanv[dl] - cnt[dl] + atomicAdd(&cnt2[dl], 1);
      if (fits) {
        if (pos >= 0 && pos < BCAP_LDS) img[pos] = v & 0x1FFFFu;
      } else {
        colbuf[segbase + pos] = (int)(v & 0x1FFFFu);
      }
    }
  }
  __syncthreads();
  if (fits) {
    for (int i = t; i < seglen; i += THREADS)
      colbuf[segbase + i] = (int)img[i];
  }
}

__global__ __launch_bounds__(THREADS) void scan1_local(const int* __restrict__ deg,
                                                       int* __restrict__ start,
                                                       int* __restrict__ blksum, int n) {
  __shared__ int sdata[THREADS];
  int i = blockIdx.x * THREADS + threadIdx.x;
  int d = (i < n) ? deg[i] : 0;
  sdata[threadIdx.x] = d;
  __syncthreads();
  for (int off = 1; off < THREADS; off <<= 1) {
    int v = (threadIdx.x >= off) ? sdata[threadIdx.x - off] : 0;
    __syncthreads();
    sdata[threadIdx.x] += v;
    __syncthreads();
  }
  if (i < n) start[i] = sdata[threadIdx.x] - d;  // local exclusive
  if (threadIdx.x == THREADS - 1) blksum[blockIdx.x] = sdata[THREADS - 1];
}

__global__ __launch_bounds__(512) void scan2_blocks(const int* __restrict__ blksum,
                                                    int* __restrict__ blkbase, int nb) {
  __shared__ int sdata[512];
  int t = threadIdx.x;
  int v = (t < nb) ? blksum[t] : 0;
  sdata[t] = v;
  __syncthreads();
  for (int off = 1; off < 512; off <<= 1) {
    int u = (t >= off) ? sdata[t - off] : 0;
    __syncthreads();
    sdata[t] += u;
    __syncthreads();
  }
  if (t < nb) blkbase[t] = sdata[t] - v;  // exclusive
}

__global__ __launch_bounds__(THREADS) void scan3_add(int* __restrict__ start,
                                                     const int* __restrict__ blkbase,
                                                     int n) {
  int i = blockIdx.x * THREADS + threadIdx.x;
  if (i < n) start[i] += blkbase[blockIdx.x];
}

__global__ __launch_bounds__(THREADS) void fill_csr_xcd(const int* __restrict__ src,
                                                        const int* __restrict__ dst,
                                                        const int* __restrict__ start,
                                                        int* __restrict__ fill,
                                                        int* __restrict__ colbuf,
                                                        int E, int rngw) {
  int g = blockIdx.x & 7;
  int chunk = blockIdx.x >> 3;
  int nchunk = gridDim.x >> 3;
  int lo = g * rngw, hi = lo + rngw;
  int stride = nchunk * THREADS;
  for (int e = chunk * THREADS + threadIdx.x; e < E; e += stride) {
    int d = dst[e];
    if (d >= lo && d < hi) {
      int p = atomicAdd(&fill[d], 1);
      colbuf[start[d] + p] = src[e];
    }
  }
}

// ---------------------------------------------------------------------------
// Pack [Wl | Wr] into MFMA B-fragment order (uint4 per (nt,kc,quad,n)).
// ---------------------------------------------------------------------------
__global__ __launch_bounds__(THREADS) void pack_weights(const float* __restrict__ Wl,
                                                        const float* __restrict__ Wr,
                                                        uint4* __restrict__ Wp) {
  int idx = blockIdx.x * THREADS + threadIdx.x;   // 0..4095
  int n = idx & 15, quad = (idx >> 4) & 3, kc = (idx >> 6) & 3, nt = idx >> 8;
  const float* W = (nt < 8) ? Wl : Wr;
  int col = ((nt & 7) * 16) + n;
  int k0 = kc * 32 + quad * 8;
  unsigned u[4];
#pragma unroll
  for (int p = 0; p < 4; ++p) {
    unsigned lo = f2bf(W[(size_t)(k0 + 2 * p) * 128 + col]);
    unsigned hi = f2bf(W[(size_t)(k0 + 2 * p + 1) * 128 + col]);
    u[p] = lo | (hi << 16);
  }
  Wp[idx] = make_uint4(u[0], u[1], u[2], u[3]);
}

// ---------------------------------------------------------------------------
// Fused dual GEMM via MFMA bf16: Cl = fp8(A'@Wl), Cr = A'@Wr + bias (fp32),
// A' = FUSE ? mask*2*relu(scsh-affine(A)) : A.
// R23 post-mortem: splitting into two dispatches doubled the A read and
// regressed (+17 µs) — reverted. R24: the dual kernel's 62 µs was L2-hit
// LATENCY on per-wave weight loads (128 × uint4 per wave at 2 waves/SIMD;
// FETCH only 26 MB = all cache-resident). All 4 waves read IDENTICAL
// weight data → stage each pass's 32 KB of Wp in LDS once per block
// (coalesced), MFMA reads via ds_read_b128. Single A read preserved.
// In-place-safe on Cr==A (band read into regs before any store).
// A-frag: A[m=lane&15][k=quad*8+j]; C/D: col=lane&15, row=quad*4+reg.
// ---------------------------------------------------------------------------
template <int FUSE>
__global__ __launch_bounds__(THREADS) void gemm_dual_mfma(
    const float* A, const uint4* __restrict__ Wp, const float* __restrict__ bias,
    const float* __restrict__ scsh, const unsigned long long* __restrict__ mask,
    unsigned char* __restrict__ Cl, float* __restrict__ Cr, int M) {
  __shared__ __align__(16) uint4 wls[2048];       // 32 KB: one pass of Wp
  int t = threadIdx.x;
  int wv = t >> 6;
  int lane = t & 63;
  int m16 = lane & 15;
  int quad = lane >> 4;
  int arow = blockIdx.x * 64 + wv * 16 + m16;     // A row this lane feeds
  bool avalid = arow < M;

  union U8 { uint4 u; bf16x8 v; };

  // stage pass-0 weights while the A-loads are in flight
#pragma unroll
  for (int i = 0; i < 8; ++i) wls[t + i * THREADS] = Wp[t + i * THREADS];

  unsigned long long m0 = 0, m1 = 0;
  if (FUSE && avalid) {
    m0 = mask[2 * (size_t)arow];
    m1 = mask[2 * (size_t)arow + 1];
  }

  bf16x8 af[4];
  const float* ap = A + (size_t)arow * 128 + quad * 8;
#pragma unroll
  for (int kc = 0; kc < 4; ++kc) {
    float v[8] = {0.f, 0.f, 0.f, 0.f, 0.f, 0.f, 0.f, 0.f};
    if (avalid) {
      *(float4*)&v[0] = *(const float4*)(ap + kc * 32);
      *(float4*)&v[4] = *(const float4*)(ap + kc * 32 + 4);
    }
    if (FUSE) {
      int col0 = kc * 32 + quad * 8;
      int shift = (col0 >> 1);                    // = kc*16 + quad*4
      unsigned e = (unsigned)(m0 >> shift) & 0xFu;
      unsigned o = (unsigned)(m1 >> shift) & 0xFu;
      bn_mask8(v, scsh, col0, e, o);
    }
    U8 u;
    u.u.x = f2bf(v[0]) | (f2bf(v[1]) << 16);
    u.u.y = f2bf(v[2]) | (f2bf(v[3]) << 16);
    u.u.z = f2bf(v[4]) | (f2bf(v[5]) << 16);
    u.u.w = f2bf(v[6]) | (f2bf(v[7]) << 16);
    af[kc] = u.v;
  }

  int orow0 = blockIdx.x * 64 + wv * 16 + quad * 4;
  const uint4* wb = wls + (quad * 16 + m16);      // + (nt*4+kc)*64

  __syncthreads();                                // pass-0 weights staged

  // ---- pass 1: nt 0..7 → Cl (fp8 e4m3) ----
  {
    f32x4 acc[8];
#pragma unroll
    for (int i = 0; i < 8; ++i) acc[i] = (f32x4){0.f, 0.f, 0.f, 0.f};
#pragma unroll
    for (int nt = 0; nt < 8; ++nt) {
#pragma unroll
      for (int kc = 0; kc < 4; ++kc) {
        U8 b;
        b.u = wb[(nt * 4 + kc) * 64];
        acc[nt] = __builtin_amdgcn_mfma_f32_16x16x32_bf16(af[kc], b.v, acc[nt], 0, 0, 0);
      }
    }
#pragma unroll
    for (int nt = 0; nt < 8; ++nt) {
      int col = nt * 16 + m16;
#pragma unroll
      for (int r = 0; r < 4; ++r) {
        int row = orow0 + r;
        if (row < M) Cl[(size_t)row * 128 + col] = f2fp8(acc[nt][r]);
      }
    }
  }

  __syncthreads();                                // pass-0 reads done
  // stage pass-1 weights
#pragma unroll
  for (int i = 0; i < 8; ++i) wls[t + i * THREADS] = Wp[2048 + t + i * THREADS];
  __syncthreads();                                // pass-1 weights staged

  // ---- pass 2: nt 8..15 → Cr (fp32 + bias) ----
  {
    f32x4 acc[8];
#pragma unroll
    for (int i = 0; i < 8; ++i) acc[i] = (f32x4){0.f, 0.f, 0.f, 0.f};
#pragma unroll
    for (int nt = 0; nt < 8; ++nt) {
#pragma unroll
      for (int kc = 0; kc < 4; ++kc) {
        U8 b;
        b.u = wb[(nt * 4 + kc) * 64];
        acc[nt] = __builtin_amdgcn_mfma_f32_16x16x32_bf16(af[kc], b.v, acc[nt], 0, 0, 0);
      }
    }
#pragma unroll
    for (int nt = 0; nt < 8; ++nt) {
      int col = nt * 16 + m16;
      float bb = bias[col];
#pragma unroll
      for (int r = 0; r < 4; ++r) {
        int row = orow0 + r;
        if (row < M) Cr[(size_t)row * 128 + col] = acc[nt][r] + bb;
      }
    }
  }
}

// ---------------------------------------------------------------------------
// Fused layer-3 projections: Cl = bf16(A'@Wl), Cr = A'@Wr + br, where
// A' = mask2*2*relu(scsh2-affine(A)) applied on load. Reads A ONCE.
// Layer-3 Cl stays BF16: its aggregate feeds `out` directly (no BN to absorb
// fp8 noise) and agg16 is cheap anyway.
// ---------------------------------------------------------------------------
__global__ __launch_bounds__(THREADS) void gemm16_dual(const float* __restrict__ A,
                                                       const float* __restrict__ Wl,
                                                       const float* __restrict__ Wr,
                                                       const float* __restrict__ br,
                                                       const float* __restrict__ scsh,
                                                       const unsigned long long* __restrict__ mask,
                                                       unsigned short* __restrict__ Cl,
                                                       float* __restrict__ Cr, int M) {
  __shared__ __align__(16) float Wls[128][16];  // [k][col]
  __shared__ __align__(16) float Wrs[128][16];
  __shared__ __align__(16) float As[16][130];   // [row][k], +2 pad
  int t = threadIdx.x;
#pragma unroll
  for (int i = 0; i < 2; ++i) {
    int lin = (t + i * THREADS) << 2;           // float4 id → float offset
    *(float4*)&Wls[0][lin & 2047] = *(const float4*)(Wl + lin);
    *(float4*)&Wrs[0][lin & 2047] = *(const float4*)(Wr + lin);
  }
  int row0 = blockIdx.x * 16;
  int r = t >> 4;     // 0..15 local row
  int c = t & 15;     // col / chunk id
  {
    int grow = row0 + r;
    float v[8] = {0.f, 0.f, 0.f, 0.f, 0.f, 0.f, 0.f, 0.f};
    if (grow < M) {
      const float* ap = A + (size_t)grow * 128 + c * 8;
      *(float4*)&v[0] = *(const float4*)(ap);
      *(float4*)&v[4] = *(const float4*)(ap + 4);
      unsigned long long m0 = mask[2 * (size_t)grow];
      unsigned long long m1 = mask[2 * (size_t)grow + 1];
      int shift = c * 4;                         // (c*8)/2
      unsigned e = (unsigned)(m0 >> shift) & 0xFu;
      unsigned o = (unsigned)(m1 >> shift) & 0xFu;
      bn_mask8(v, scsh, c * 8, e, o);
    }
    *(float4*)&As[r][c * 8] = *(float4*)&v[0];
    *(float4*)&As[r][c * 8 + 4] = *(float4*)&v[4];
  }
  __syncthreads();
  float accl = 0.f, accr = 0.f;
#pragma unroll 4
  for (int k = 0; k < 128; ++k) {
    float a = As[r][k];                          // broadcast across 16 lanes
    accl += a * Wls[k][c];
    accr += a * Wrs[k][c];
  }
  int grow = row0 + r;
  if (grow < M) {
    Cl[(size_t)grow * 16 + c] = (unsigned short)f2bf(accl);
    Cr[(size_t)grow * 16 + c] = accr + br[c];
  }
}

// ---------------------------------------------------------------------------
// Z[n] (fp32) += agg(Yfp8)[n] / max(deg,1): one wave per node; the wave's
// two 32-lane halves process two edges per instruction; lane covers 4 fp8
// cols (uint load = whole 128 B row per half). fp8 rows = 2 lines/edge
// (R10 win). HW pk decode fp8→f32. Cross-half combine via __shfl; lanes
// 0..31 do the float4 Z update. R21: threefry moved out; 16-edge unroll.
// ---------------------------------------------------------------------------
__global__ __launch_bounds__(THREADS) void aggregate128_fp8(
    const unsigned char* __restrict__ Y, float* __restrict__ Z,
    const int* __restrict__ colbuf, const int* __restrict__ start,
    const int* __restrict__ deg, int nnodes) {
  int w = (blockIdx.x * THREADS + threadIdx.x) >> 6;  // node = global wave id
  int lane = threadIdx.x & 63;
  if (w >= nnodes) return;
  int half = lane >> 5;         // 0: even edge of pair, 1: odd edge
  int l32 = lane & 31;
  const int* cb = colbuf + start[w];
  int dg = deg[w];
  const unsigned char* yp = Y + (l32 << 2);      // 4 fp8 cols per lane
  float a0f = 0.f, a1f = 0.f, a2f = 0.f, a3f = 0.f;
  int i = 0;
#define ACC(u) { \
    f32x2 lo = __builtin_amdgcn_cvt_pk_f32_fp8((int)(u), false); \
    f32x2 hi = __builtin_amdgcn_cvt_pk_f32_fp8((int)(u), true);  \
    a0f += lo.x; a1f += lo.y; a2f += hi.x; a3f += hi.y; }
  for (; i + 16 <= dg; i += 16) {                // 16 edges = 8 loads in flight
    int e0 = cb[i + half], e1 = cb[i + 2 + half];
    int e2 = cb[i + 4 + half], e3 = cb[i + 6 + half];
    int e4 = cb[i + 8 + half], e5 = cb[i + 10 + half];
    int e6 = cb[i + 12 + half], e7 = cb[i + 14 + half];
    unsigned u0 = *(const unsigned*)(yp + (size_t)e0 * 128);
    unsigned u1 = *(const unsigned*)(yp + (size_t)e1 * 128);
    unsigned u2 = *(const unsigned*)(yp + (size_t)e2 * 128);
    unsigned u3 = *(const unsigned*)(yp + (size_t)e3 * 128);
    unsigned u4 = *(const unsigned*)(yp + (size_t)e4 * 128);
    unsigned u5 = *(const unsigned*)(yp + (size_t)e5 * 128);
    unsigned u6 = *(const unsigned*)(yp + (size_t)e6 * 128);
    unsigned u7 = *(const unsigned*)(yp + (size_t)e7 * 128);
    ACC(u0) ACC(u1) ACC(u2) ACC(u3) ACC(u4) ACC(u5) ACC(u6) ACC(u7)
  }
  for (; i + 8 <= dg; i += 8) {                  // 8 edges = 4 uint loads/lane
    int e0 = cb[i + half], e1 = cb[i + 2 + half];
    int e2 = cb[i + 4 + half], e3 = cb[i + 6 + half];
    unsigned u0 = *(const unsigned*)(yp + (size_t)e0 * 128);
    unsigned u1 = *(const unsigned*)(yp + (size_t)e1 * 128);
    unsigned u2 = *(const unsigned*)(yp + (size_t)e2 * 128);
    unsigned u3 = *(const unsigned*)(yp + (size_t)e3 * 128);
    ACC(u0) ACC(u1) ACC(u2) ACC(u3)
  }
  for (; i + 2 <= dg; i += 2) {
    int e0 = cb[i + half];
    unsigned u0 = *(const unsigned*)(yp + (size_t)e0 * 128);
    ACC(u0)
  }
  if (i < dg) {                                  // odd tail: half 0 only
    int e0 = cb[i];
    unsigned u0 = *(const unsigned*)(yp + (size_t)e0 * 128);
    if (half == 0) { ACC(u0) }
  }
#undef ACC
  // combine halves: lanes 0..31 += lanes 32..63 (same cols)
  a0f += __shfl(a0f, lane + 32);
  a1f += __shfl(a1f, lane + 32);
  a2f += __shfl(a2f, lane + 32);
  a3f += __shfl(a3f, lane + 32);

  if (half == 0) {
    float sc = 1.0f / fmaxf((float)dg, 1.0f);
    float* zp = Z + (size_t)w * 128 + (l32 << 2);
    float4 z = *(const float4*)zp;
    z.x += a0f * sc;
    z.y += a1f * sc;
    z.z += a2f * sc;
    z.w += a3f * sc;
    *(float4*)zp = z;
  }
}

// Out[n] += agg(Y16bf16)[n] / max(deg,1): 8 threads/node, ×8 edge unroll.
__global__ __launch_bounds__(THREADS) void aggregate16_bf16(
    const unsigned short* __restrict__ Y, float* __restrict__ Out,
    const int* __restrict__ colbuf, const int* __restrict__ start,
    const int* __restrict__ deg, int nnodes) {
  int gid = blockIdx.x * THREADS + threadIdx.x;
  int n = gid >> 3;
  int cp = gid & 7;             // col pair: cols 2cp, 2cp+1
  if (n >= nnodes) return;
  const int* cb = colbuf + start[n];
  int dg = deg[n];
  const unsigned short* yp = Y + (cp << 1);
  float ax = 0.f, ay = 0.f;
  int i = 0;
  for (; i + 8 <= dg; i += 8) {
    int e[8];
#pragma unroll
    for (int j = 0; j < 8; ++j) e[j] = cb[i + j];
    unsigned u[8];
#pragma unroll
    for (int j = 0; j < 8; ++j) u[j] = *(const unsigned*)(yp + (size_t)e[j] * 16);
#pragma unroll
    for (int j = 0; j < 8; ++j) {
      ax += __uint_as_float(u[j] << 16);
      ay += __uint_as_float(u[j] & 0xffff0000u);
    }
  }
  for (; i < dg; ++i) {
    unsigned u = *(const unsigned*)(yp + (size_t)cb[i] * 16);
    ax += __uint_as_float(u << 16);
    ay += __uint_as_float(u & 0xffff0000u);
  }
  float sc = 1.0f / fmaxf((float)dg, 1.0f);
  size_t off = (size_t)n * 16 + (cp << 1);
  float2 o = *(const float2*)(Out + off);
  o.x += ax * sc;
  o.y += ay * sc;
  *(float2*)(Out + off) = o;
}

// ---------------------------------------------------------------------------
// BN stats + dropout mask gen (R21 move; R22 ILP fix — measured good).
// 4 rows per iteration with 4 INDEPENDENT threefry chains — ILP covers the
// VALU dep latency. Wave scheme (bit-identical masks): wave parity p,
// lane l → element r*128+2l+p → ballot → mask[2r+p].
// ---------------------------------------------------------------------------
__global__ __launch_bounds__(THREADS) void bn_stats(const float* __restrict__ H,
                                                    float* __restrict__ sums,
                                                    unsigned long long* __restrict__ mask,
                                                    unsigned mk0, unsigned mk1,
                                                    int n) {
  int col = threadIdx.x & 127;
  int half = threadIdx.x >> 7;  // 0/1 (wave-uniform)
  int lane = threadIdx.x & 63;
  unsigned parity = (threadIdx.x >> 6) & 1u;  // wave-uniform
  unsigned base = ((unsigned)lane << 1) + parity;
  float s = 0.f, sq = 0.f;
  int stride = gridDim.x * 2;
  int r = blockIdx.x * 2 + half;
  // 4-row main loop: independent tf chains give the VALU ILP
  for (; r + 3 * stride < n; r += 4 * stride) {
    int r0 = r, r1 = r + stride, r2 = r + 2 * stride, r3 = r + 3 * stride;
    float v0 = H[(size_t)r0 * 128 + col];
    float v1 = H[(size_t)r1 * 128 + col];
    float v2 = H[(size_t)r2 * 128 + col];
    float v3 = H[(size_t)r3 * 128 + col];
    s += v0 + v1 + v2 + v3;
    sq += v0 * v0 + v1 * v1 + v2 * v2 + v3 * v3;
    unsigned a0, a1, b0, b1, c0, c1, d0, d1;
    tf2x32(mk0, mk1, 0u, (unsigned)r0 * 128u + base, &a0, &a1);
    tf2x32(mk0, mk1, 0u, (unsigned)r1 * 128u + base, &b0, &b1);
    tf2x32(mk0, mk1, 0u, (unsigned)r2 * 128u + base, &c0, &c1);
    tf2x32(mk0, mk1, 0u, (unsigned)r3 * 128u + base, &d0, &d1);
    unsigned long long m0b = __ballot(((a0 ^ a1) >> 31) == 0u);
    unsigned long long m1b = __ballot(((b0 ^ b1) >> 31) == 0u);
    unsigned long long m2b = __ballot(((c0 ^ c1) >> 31) == 0u);
    unsigned long long m3b = __ballot(((d0 ^ d1) >> 31) == 0u);
    if (lane == 0) {
      mask[2 * (size_t)r0 + parity] = m0b;
      mask[2 * (size_t)r1 + parity] = m1b;
      mask[2 * (size_t)r2 + parity] = m2b;
      mask[2 * (size_t)r3 + parity] = m3b;
    }
  }
  for (; r < n; r += stride) {
    float v = H[(size_t)r * 128 + col];
    s += v;
    sq += v * v;
    unsigned o0, o1;
    tf2x32(mk0, mk1, 0u, (unsigned)r * 128u + base, &o0, &o1);
    unsigned long long bm = __ballot(((o0 ^ o1) >> 31) == 0u);
    if (lane == 0) mask[2 * (size_t)r + parity] = bm;
  }
  __shared__ float ls[THREADS], lq[THREADS];
  ls[threadIdx.x] = s;
  lq[threadIdx.x] = sq;
  __syncthreads();
  if (half == 0) {
    s += ls[col + 128];
    sq += lq[col + 128];
    atomicAdd(&sums[col], s);
    atomicAdd(&sums[128 + col], sq);
  }
}

__global__ void bn_finalize(const float* __restrict__ sums,
                            const float* __restrict__ g,
                            const float* __restrict__ be,
                            float* __restrict__ scsh, float n) {
  int c = threadIdx.x;  // 128 threads
  float mu = sums[c] / n;
  float var = sums[128 + c] / n - mu * mu;
  float inv = rsqrtf(var + 1e-5f);
  float sc = g[c] * inv;
  scsh[c] = sc;
  scsh[128 + c] = be[c] - mu * sc;
}

// ---------------------------------------------------------------------------
// Launch. R24: back to the R22 dual-GEMM structure (R23 split reverted);
// gemm_dual_mfma now LDS-stages each pass's 32 KB of weights per block.
// Everything else identical to the R22-measured build (493.7 µs).
// ---------------------------------------------------------------------------
extern "C" void kernel_launch(void* const* d_in, const int* in_sizes, int n_in,
                              void* d_out, int out_size, void* d_ws, size_t ws_size,
                              hipStream_t stream) {
  const float* x   = (const float*)d_in[0];
  const int* eidx  = (const int*)d_in[1];
  const float* W1l = (const float*)d_in[2];
  const float* W1r = (const float*)d_in[3];
  const float* b1  = (const float*)d_in[4];
  const float* g1  = (const float*)d_in[5];
  const float* be1 = (const float*)d_in[6];
  const float* W2l = (const float*)d_in[7];
  const float* W2r = (const float*)d_in[8];
  const float* b2  = (const float*)d_in[9];
  const float* g2  = (const float*)d_in[10];
  const float* be2 = (const float*)d_in[11];
  const float* W3l = (const float*)d_in[12];
  const float* W3r = (const float*)d_in[13];
  const float* b3  = (const float*)d_in[14];
  float* out = (float*)d_out;

  const int N = in_sizes[0] / 128;
  const int E = in_sizes[1] / 2;
  const int* esrc = eidx;
  const int* edst = eidx + E;

  size_t N128 = (size_t)N * 128;
  size_t Nw = ((size_t)N + 63) & ~(size_t)63;   // padded node count (words)
  size_t Ew = ((size_t)E + 63) & ~(size_t)63;   // padded edge count (words)

  // Cleared region first (one memset): sums1(256) sums2(256) ideg(N) ifill(N)
  float* sums1 = (float*)d_ws;
  float* sums2 = sums1 + 256;
  int* ideg    = (int*)(sums2 + 256);
  int* ifill   = ideg + N;                    // strided bump counters
  // Uncleared (all region sizes padded to multiples of 64 words → every base
  // below is ≥256 B-aligned):
  int* istart  = ifill + N;
  int* iblksum = istart + (int)Nw;            // 512
  int* iblkbase = iblksum + 512;              // 512
  int* bbase   = iblkbase + 512;              // 1088 (bucket-base scan)
  float* scsh1 = (float*)(bbase + 1088);      // 256
  float* scsh2 = scsh1 + 256;                 // 256
  uint4* wp1 = (uint4*)(scsh2 + 256);         // 4096 uint4 each = 64 KB
  uint4* wp2 = wp1 + 4096;
  unsigned long long* mask1 = (unsigned long long*)(wp2 + 4096);  // N×2 u64
  unsigned long long* mask2 = mask1 + 2 * Nw;
  int* icol  = (int*)(mask2 + 2 * Nw);        // E ints
  // buf0: fp8 N×128 B (layers 1-2) / bf16 N×16 (layer 3). 12.8 MB, padded.
  unsigned char* buf0b = (unsigned char*)(icol + Ew);
  unsigned short* buf0h = (unsigned short*)buf0b;
  float* buf1 = (float*)(buf0b + ((N128 + 255) & ~(size_t)255)); // fp32 h-state N×128

  // Bucket storage: overlays buf0/buf1 (dead during CSR build).
  unsigned* buckets = (unsigned*)buf0b;
  int nbk = (N + 127) >> 7;                   // 128-node buckets
  int bcap = 1024;                            // per-(group,bucket) capacity
  size_t bucket_bytes = (size_t)8 * nbk * bcap * 4;
  size_t bufregion_bytes = ((N128 + 255) & ~(size_t)255) + 4 * N128;
  bool newcsr = (N <= 131072) && (nbk <= 1023) &&
                ((size_t)64 * nbk <= (size_t)N) &&   // counters fit cleared region
                (bucket_bytes <= bufregion_bytes);

  // dropout keys: k1,k2 = split(key(42)) under partitionable threefry
  unsigned k1a, k1b, k2a, k2b;
  tf2x32(0u, 42u, 0u, 0u, &k1a, &k1b);
  tf2x32(0u, 42u, 0u, 1u, &k2a, &k2b);

  hipMemsetAsync(sums1, 0, (512 + 2 * (size_t)N) * 4, stream);

  pack_weights<<<16, THREADS, 0, stream>>>(W1l, W1r, wp1);
  pack_weights<<<16, THREADS, 0, stream>>>(W2l, W2r, wp2);

  int gN = (N + THREADS - 1) / THREADS;      // == #scan blocks, must be <=512
  if (newcsr) {
    int e8 = (((E + 7) / 8) + 3) & ~3;       // 4-aligned per-group edge range
    bin_edges3<<<512, THREADS, 0, stream>>>(esrc, edst, (unsigned*)ifill,
                                            buckets, bcap, nbk, E, e8,
                                            (unsigned)N);
    scan_buckets<<<1, 1024, 0, stream>>>((const unsigned*)ifill, bbase,
                                         bcap, nbk);
    scatter_csr2<<<nbk, THREADS, 0, stream>>>(buckets, (const unsigned*)ifill,
                                              bbase, ideg, istart, icol,
                                              bcap, nbk, N);
  } else {
    int gE = (E + THREADS - 1) / THREADS;
    compute_deg<<<gE, THREADS, 0, stream>>>(edst, ideg, E);
    scan1_local<<<gN, THREADS, 0, stream>>>(ideg, istart, iblksum, N);
    scan2_blocks<<<1, 512, 0, stream>>>(iblksum, iblkbase, gN);
    scan3_add<<<gN, THREADS, 0, stream>>>(istart, iblkbase, N);
    int rngw = (N + 7) / 8;
    fill_csr_xcd<<<2048, THREADS, 0, stream>>>(esrc, edst, istart, ifill, icol, E, rngw);
  }

  int gM64 = (N + 63) / 64;
  int gW = (N + 3) / 4;                 // aggregate128: 4 waves/block
  int gA16 = (N * 8 + THREADS - 1) / THREADS;
  float nf = (float)N;

  // ---- Layer 1 ----
  gemm_dual_mfma<0><<<gM64, THREADS, 0, stream>>>(x, wp1, b1, nullptr, nullptr,
                                                  buf0b, buf1, N);
  aggregate128_fp8<<<gW, THREADS, 0, stream>>>(buf0b, buf1, icol, istart, ideg, N);
  bn_stats<<<1024, THREADS, 0, stream>>>(buf1, sums1, mask1, k1a, k1b, N);
  bn_finalize<<<1, 128, 0, stream>>>(sums1, g1, be1, scsh1, nf);

  // ---- Layer 2 (BN1+ReLU+drop1 via scsh1+mask1; Cr in-place on buf1) ----
  gemm_dual_mfma<1><<<gM64, THREADS, 0, stream>>>(buf1, wp2, b2, scsh1, mask1,
                                                  buf0b, buf1, N);
  aggregate128_fp8<<<gW, THREADS, 0, stream>>>(buf0b, buf1, icol, istart, ideg, N);
  bn_stats<<<1024, THREADS, 0, stream>>>(buf1, sums2, mask2, k2a, k2b, N);
  bn_finalize<<<1, 128, 0, stream>>>(sums2, g2, be2, scsh2, nf);

  // ---- Layer 3 (BN2+ReLU+drop2 via scsh2+mask2 in dual 16-wide GEMM) ----
  gemm16_dual<<<(N + 15) / 16, THREADS, 0, stream>>>(buf1, W3l, W3r, b3, scsh2,
                                                     mask2, buf0h, out, N);
  aggregate16_bf16<<<gA16, THREADS, 0, stream>>>(buf0h, out, icol, istart, ideg, N);
}